// Round 1
// baseline (363.639 us; speedup 1.0000x reference)
//
#include <hip/hip_runtime.h>
#include <hip/hip_bf16.h>
#include <type_traits>

typedef unsigned short u16;
typedef __attribute__((ext_vector_type(8))) short  s16x8;
typedef __attribute__((ext_vector_type(8))) __bf16 b16x8;
typedef __attribute__((ext_vector_type(4))) float  f32x4;

#define S_LEN 4096
#define NB    4
#define EMB   1024
#define NH    16
#define HD    64
#define NROWS (NB * S_LEN)   // 16384

static __device__ __forceinline__ u16 f2b(float f) {
  __hip_bfloat16 h = __float2bfloat16(f);
  return __builtin_bit_cast(u16, h);
}

// ---- MFMA shim: works whether the builtin takes short8 or bf16x8 ----
template <typename T, typename = void>
struct mfma_takes : std::false_type {};
template <typename T>
struct mfma_takes<T, std::void_t<decltype(__builtin_amdgcn_mfma_f32_16x16x32_bf16(
    std::declval<T>(), std::declval<T>(), std::declval<f32x4>(), 0, 0, 0))>> : std::true_type {};

template <typename AB>
static __device__ __forceinline__ f32x4 mfma_any(AB a, AB b, f32x4 c) {
  return __builtin_amdgcn_mfma_f32_16x16x32_bf16(a, b, c, 0, 0, 0);
}

template <typename S8 = s16x8, typename B8 = b16x8>
static __device__ __forceinline__ f32x4 MFMA_BF16(s16x8 a, s16x8 b, f32x4 c) {
  if constexpr (mfma_takes<S8>::value)
    return mfma_any<S8>(__builtin_bit_cast(S8, a), __builtin_bit_cast(S8, b), c);
  else
    return mfma_any<B8>(__builtin_bit_cast(B8, a), __builtin_bit_cast(B8, b), c);
}

static __device__ __forceinline__ void gld_lds16(const void* g, void* l) {
  __builtin_amdgcn_global_load_lds((const __attribute__((address_space(1))) void*)g,
                                   (__attribute__((address_space(3))) void*)l, 16, 0, 0);
}

// ---------------- fp32 -> bf16 conversion (x) ----------------
__global__ __launch_bounds__(256) void cvt_x_kernel(const float* __restrict__ in,
                                                    u16* __restrict__ out) {
  long i = ((long)blockIdx.x * 256 + threadIdx.x) * 8;
  float4 a = *(const float4*)(in + i);
  float4 b = *(const float4*)(in + i + 4);
  s16x8 o;
  o[0] = (short)f2b(a.x); o[1] = (short)f2b(a.y); o[2] = (short)f2b(a.z); o[3] = (short)f2b(a.w);
  o[4] = (short)f2b(b.x); o[5] = (short)f2b(b.y); o[6] = (short)f2b(b.z); o[7] = (short)f2b(b.w);
  *(s16x8*)(out + i) = o;
}

// ---------------- transpose + convert W (1024x1024) ----------------
__global__ __launch_bounds__(256) void transpose_cvt_kernel(const float* __restrict__ W,
                                                            u16* __restrict__ Wt) {
  __shared__ float tile[32][33];
  int n0 = blockIdx.x * 32, k0 = blockIdx.y * 32;
  int tx = threadIdx.x & 31, ty = threadIdx.x >> 5;
#pragma unroll
  for (int i = ty; i < 32; i += 8)
    tile[i][tx] = W[(long)(k0 + i) * EMB + n0 + tx];
  __syncthreads();
#pragma unroll
  for (int i = ty; i < 32; i += 8)
    Wt[(long)(n0 + i) * EMB + k0 + tx] = f2b(tile[tx][i]);
}

// ---------------- bf16 GEMM: C(MxN) = A(MxK) * Bt(NxK)^T + bias ----------------
#define BM 128
#define BN 128
#define BK 64

__global__ __launch_bounds__(256) void gemm_bt_kernel(
    const u16* __restrict__ A, const u16* __restrict__ Bt,
    const float* __restrict__ b0, const float* __restrict__ b1, const float* __restrict__ b2,
    void* __restrict__ Cp, int M, int N, int K, int out_f32) {
  __shared__ u16 lA[BM * BK];
  __shared__ u16 lB[BN * BK];
  const int tid = threadIdx.x;
  const int w = tid >> 6, lane = tid & 63;
  const int nbn = N / BN;
  const int bm = blockIdx.x / nbn, bn = blockIdx.x % nbn;

  const int rw = (w >> 1) * 64;
  const int cw = (w & 1) * 64;

  f32x4 acc[4][4];
#pragma unroll
  for (int m = 0; m < 4; m++)
#pragma unroll
    for (int n = 0; n < 4; n++) acc[m][n] = (f32x4)0.0f;

  // staging: wave-uniform LDS base + lane*16B, inverse-swizzled global source
  const int srow = w * 32 + (lane >> 3);               // + i*8
  const int schunk = (lane & 7) ^ (lane >> 3);         // pre-swizzled source chunk
  const long arow_base = (long)(bm * BM + srow) * K;
  const long brow_base = (long)(bn * BN + srow) * K;

  const int frow = lane & 15;
  const int fg = lane >> 4;

  for (int k0 = 0; k0 < K; k0 += BK) {
#pragma unroll
    for (int i = 0; i < 4; i++) {
      gld_lds16(A + arow_base + (long)i * 8 * K + k0 + schunk * 8,
                &lA[(w * 32 + i * 8) * BK]);
      gld_lds16(Bt + brow_base + (long)i * 8 * K + k0 + schunk * 8,
                &lB[(w * 32 + i * 8) * BK]);
    }
    __syncthreads();
#pragma unroll
    for (int kk = 0; kk < 2; kk++) {
      s16x8 af[4], bfr[4];
#pragma unroll
      for (int m = 0; m < 4; m++) {
        int r = rw + 16 * m + frow;
        int ch = (fg + 4 * kk) ^ (r & 7);
        af[m] = *(const s16x8*)&lA[r * BK + ch * 8];
      }
#pragma unroll
      for (int n = 0; n < 4; n++) {
        int r = cw + 16 * n + frow;
        int ch = (fg + 4 * kk) ^ (r & 7);
        bfr[n] = *(const s16x8*)&lB[r * BK + ch * 8];
      }
#pragma unroll
      for (int m = 0; m < 4; m++)
#pragma unroll
        for (int n = 0; n < 4; n++)
          acc[m][n] = MFMA_BF16(af[m], bfr[n], acc[m][n]);
    }
    __syncthreads();
  }

  // epilogue (C/D layout: col = lane&15, row = (lane>>4)*4 + reg)
  const int gr0 = bm * BM + rw + 4 * fg;
  const int gc0 = bn * BN + cw + frow;
#pragma unroll
  for (int n = 0; n < 4; n++) {
    int gc = gc0 + 16 * n;
    int which = gc >> 10;
    const float* bias = (which == 0) ? b0 : ((which == 1) ? b1 : b2);
    float bv = bias[gc & 1023];
#pragma unroll
    for (int m = 0; m < 4; m++) {
      int gr = gr0 + 16 * m;
#pragma unroll
      for (int r = 0; r < 4; r++) {
        float v = acc[m][n][r] + bv;
        long off = (long)(gr + r) * N + gc;
        if (out_f32) ((float*)Cp)[off] = v;
        else ((u16*)Cp)[off] = f2b(v);
      }
    }
  }
}

// ---------------- local attention ----------------
#define QBLK 128
#define LPITCH 72

__global__ __launch_bounds__(256) void attn_kernel(const u16* __restrict__ QKV,
                                                   u16* __restrict__ Oa) {
  __shared__ u16 lK[64 * LPITCH];
  __shared__ u16 lV[64 * LPITCH];          // transposed: lV[d][kv]
  __shared__ u16 lP[4 * 32 * LPITCH];

  const int tid = threadIdx.x;
  const int w = tid >> 6, lane = tid & 63;
  const int frow = lane & 15, fg = lane >> 4;

  const int nq = S_LEN / QBLK;             // 32
  const int bid = blockIdx.x;
  const int b = bid / (NH * nq);
  const int rem = bid % (NH * nq);
  const int h = rem / nq;
  const int qt = rem % nq;
  const int q0 = qt * QBLK;
  const int qw0 = q0 + 32 * w;

  const u16* base = QKV + (long)b * S_LEN * 3072 + h * 64;

  s16x8 qf[2][2];
#pragma unroll
  for (int m = 0; m < 2; m++)
#pragma unroll
    for (int kk = 0; kk < 2; kk++)
      qf[m][kk] = *(const s16x8*)(base + (long)(qw0 + 16 * m + frow) * 3072 + kk * 32 + 8 * fg);

  f32x4 acc[2][4];
#pragma unroll
  for (int m = 0; m < 2; m++)
#pragma unroll
    for (int n = 0; n < 4; n++) acc[m][n] = (f32x4)0.0f;
  float mrow[2][4], lrow[2][4];
#pragma unroll
  for (int m = 0; m < 2; m++)
#pragma unroll
    for (int rg = 0; rg < 4; rg++) { mrow[m][rg] = -1e30f; lrow[m][rg] = 0.f; }

  u16* lPw = &lP[w * 32 * LPITCH];

  for (int t = 0; t < 6; t++) {
    const int kvb = q0 - 128 + t * 64;
    if (kvb + 63 < 0 || kvb >= S_LEN) continue;   // block-uniform
    {
      const int srow = tid >> 3;
      const int sc8 = tid & 7;
#pragma unroll
      for (int pass = 0; pass < 2; pass++) {
        int row = srow + pass * 32;
        int kv = kvb + row;
        s16x8 kd = (s16x8)0, vd = (s16x8)0;
        if (kv >= 0 && kv < S_LEN) {
          kd = *(const s16x8*)(base + 1024 + (long)kv * 3072 + sc8 * 8);
          vd = *(const s16x8*)(base + 2048 + (long)kv * 3072 + sc8 * 8);
        }
        *(s16x8*)&lK[row * LPITCH + sc8 * 8] = kd;
#pragma unroll
        for (int j = 0; j < 8; j++) lV[(sc8 * 8 + j) * LPITCH + row] = (u16)vd[j];
      }
    }
    __syncthreads();
    const bool active = (kvb + 63 >= qw0 - 128) && (kvb <= qw0 + 159);
    if (active) {
      f32x4 sfr[2][4];
#pragma unroll
      for (int m = 0; m < 2; m++)
#pragma unroll
        for (int n = 0; n < 4; n++) sfr[m][n] = (f32x4)0.0f;
#pragma unroll
      for (int kk = 0; kk < 2; kk++) {
        s16x8 kb[4];
#pragma unroll
        for (int n = 0; n < 4; n++)
          kb[n] = *(const s16x8*)&lK[(16 * n + frow) * LPITCH + (fg + 4 * kk) * 8];
#pragma unroll
        for (int m = 0; m < 2; m++)
#pragma unroll
          for (int n = 0; n < 4; n++)
            sfr[m][n] = MFMA_BF16(qf[m][kk], kb[n], sfr[m][n]);
      }
#pragma unroll
      for (int m = 0; m < 2; m++) {
#pragma unroll
        for (int rg = 0; rg < 4; rg++) {
          const int q = qw0 + 16 * m + 4 * fg + rg;
          float sv[4];
          float smax = -1e30f;
#pragma unroll
          for (int n = 0; n < 4; n++) {
            int kv = kvb + 16 * n + frow;
            bool valid = (kv >= q - 128) && (kv <= q + 128) && (kv >= 0) && (kv < S_LEN);
            float xv = valid ? sfr[m][n][rg] * 0.125f : -1e30f;
            sv[n] = xv;
            smax = fmaxf(smax, xv);
          }
          smax = fmaxf(smax, __shfl_xor(smax, 1));
          smax = fmaxf(smax, __shfl_xor(smax, 2));
          smax = fmaxf(smax, __shfl_xor(smax, 4));
          smax = fmaxf(smax, __shfl_xor(smax, 8));
          float mold = mrow[m][rg];
          float mnew = fmaxf(mold, smax);
          float alpha = __expf(mold - mnew);
          mrow[m][rg] = mnew;
          float psum = 0.f;
#pragma unroll
          for (int n = 0; n < 4; n++) {
            float p = (sv[n] > -1e29f) ? __expf(sv[n] - mnew) : 0.f;
            psum += p;
            lPw[(16 * m + 4 * fg + rg) * LPITCH + 16 * n + frow] = f2b(p);
          }
          psum += __shfl_xor(psum, 1);
          psum += __shfl_xor(psum, 2);
          psum += __shfl_xor(psum, 4);
          psum += __shfl_xor(psum, 8);
          lrow[m][rg] = lrow[m][rg] * alpha + psum;
#pragma unroll
          for (int n = 0; n < 4; n++) acc[m][n][rg] *= alpha;
        }
      }
      __threadfence_block();
#pragma unroll
      for (int kt = 0; kt < 2; kt++) {
        s16x8 pa[2], vb[4];
#pragma unroll
        for (int m = 0; m < 2; m++)
          pa[m] = *(const s16x8*)&lPw[(16 * m + frow) * LPITCH + (fg + 4 * kt) * 8];
#pragma unroll
        for (int n = 0; n < 4; n++)
          vb[n] = *(const s16x8*)&lV[(16 * n + frow) * LPITCH + (fg + 4 * kt) * 8];
#pragma unroll
        for (int m = 0; m < 2; m++)
#pragma unroll
          for (int n = 0; n < 4; n++)
            acc[m][n] = MFMA_BF16(pa[m], vb[n], acc[m][n]);
      }
    }
    __syncthreads();
  }
#pragma unroll
  for (int m = 0; m < 2; m++) {
#pragma unroll
    for (int rg = 0; rg < 4; rg++) {
      const int q = qw0 + 16 * m + 4 * fg + rg;
      const float inv = 1.0f / lrow[m][rg];
#pragma unroll
      for (int n = 0; n < 4; n++)
        Oa[((long)(b * S_LEN + q)) * EMB + h * HD + 16 * n + frow] = f2b(acc[m][n][rg] * inv);
    }
  }
}

extern "C" void kernel_launch(void* const* d_in, const int* in_sizes, int n_in,
                              void* d_out, int out_size, void* d_ws, size_t ws_size,
                              hipStream_t stream) {
  const float* x  = (const float*)d_in[0];
  const float* Wq = (const float*)d_in[1];
  const float* bq = (const float*)d_in[2];
  const float* Wk = (const float*)d_in[3];
  const float* bk = (const float*)d_in[4];
  const float* Wv = (const float*)d_in[5];
  const float* bv = (const float*)d_in[6];
  const float* Wo = (const float*)d_in[7];
  const float* bo = (const float*)d_in[8];

  char* ws = (char*)d_ws;
  u16* xb   = (u16*)ws;  ws += (size_t)NROWS * EMB * 2;        // 32 MB
  u16* Wt   = (u16*)ws;  ws += (size_t)3 * EMB * EMB * 2;      // 6 MB
  u16* Wot  = (u16*)ws;  ws += (size_t)EMB * EMB * 2;          // 2 MB
  u16* QKVb = (u16*)ws;  ws += (size_t)NROWS * 3 * EMB * 2;    // 96 MB
  u16* Oab  = (u16*)ws;  ws += (size_t)NROWS * EMB * 2;        // 32 MB

  cvt_x_kernel<<<(NROWS * EMB) / (256 * 8), 256, 0, stream>>>(x, xb);

  dim3 tg(EMB / 32, EMB / 32);
  transpose_cvt_kernel<<<tg, 256, 0, stream>>>(Wq, Wt);
  transpose_cvt_kernel<<<tg, 256, 0, stream>>>(Wk, Wt + (size_t)EMB * EMB);
  transpose_cvt_kernel<<<tg, 256, 0, stream>>>(Wv, Wt + (size_t)2 * EMB * EMB);
  transpose_cvt_kernel<<<tg, 256, 0, stream>>>(Wo, Wot);

  gemm_bt_kernel<<<(NROWS / BM) * (3 * EMB / BN), 256, 0, stream>>>(
      xb, Wt, bq, bk, bv, QKVb, NROWS, 3 * EMB, EMB, 0);

  attn_kernel<<<NB * NH * (S_LEN / QBLK), 256, 0, stream>>>(QKVb, Oab);

  gemm_bt_kernel<<<(NROWS / BM) * (EMB / BN), 256, 0, stream>>>(
      Oab, Wot, bo, bo, bo, d_out, NROWS, EMB, EMB, 1);
}

// Round 2
// 331.511 us; speedup vs baseline: 1.0969x; 1.0969x over previous
//
#include <hip/hip_runtime.h>
#include <hip/hip_bf16.h>
#include <type_traits>

typedef unsigned short u16;
typedef __attribute__((ext_vector_type(8))) short  s16x8;
typedef __attribute__((ext_vector_type(8))) __bf16 b16x8;
typedef __attribute__((ext_vector_type(4))) float  f32x4;

#define S_LEN 4096
#define NB    4
#define EMB   1024
#define NH    16
#define HD    64
#define NROWS (NB * S_LEN)   // 16384

static __device__ __forceinline__ u16 f2b(float f) {
  __hip_bfloat16 h = __float2bfloat16(f);
  return __builtin_bit_cast(u16, h);
}

// ---- MFMA shim: works whether the builtin takes short8 or bf16x8 ----
template <typename T, typename = void>
struct mfma_takes : std::false_type {};
template <typename T>
struct mfma_takes<T, std::void_t<decltype(__builtin_amdgcn_mfma_f32_16x16x32_bf16(
    std::declval<T>(), std::declval<T>(), std::declval<f32x4>(), 0, 0, 0))>> : std::true_type {};

template <typename AB>
static __device__ __forceinline__ f32x4 mfma_any(AB a, AB b, f32x4 c) {
  return __builtin_amdgcn_mfma_f32_16x16x32_bf16(a, b, c, 0, 0, 0);
}

template <typename S8 = s16x8, typename B8 = b16x8>
static __device__ __forceinline__ f32x4 MFMA_BF16(s16x8 a, s16x8 b, f32x4 c) {
  if constexpr (mfma_takes<S8>::value)
    return mfma_any<S8>(__builtin_bit_cast(S8, a), __builtin_bit_cast(S8, b), c);
  else
    return mfma_any<B8>(__builtin_bit_cast(B8, a), __builtin_bit_cast(B8, b), c);
}

static __device__ __forceinline__ void gld_lds16(const void* g, void* l) {
  __builtin_amdgcn_global_load_lds((const __attribute__((address_space(1))) void*)g,
                                   (__attribute__((address_space(3))) void*)l, 16, 0, 0);
}

// ---------------- fp32 -> bf16 conversion (x) ----------------
__global__ __launch_bounds__(256) void cvt_x_kernel(const float* __restrict__ in,
                                                    u16* __restrict__ out) {
  long i = ((long)blockIdx.x * 256 + threadIdx.x) * 8;
  float4 a = *(const float4*)(in + i);
  float4 b = *(const float4*)(in + i + 4);
  s16x8 o;
  o[0] = (short)f2b(a.x); o[1] = (short)f2b(a.y); o[2] = (short)f2b(a.z); o[3] = (short)f2b(a.w);
  o[4] = (short)f2b(b.x); o[5] = (short)f2b(b.y); o[6] = (short)f2b(b.z); o[7] = (short)f2b(b.w);
  *(s16x8*)(out + i) = o;
}

// ---------------- transpose + convert 4 x W (1024x1024), fused ----------------
__global__ __launch_bounds__(256) void transpose_cvt4_kernel(
    const float* __restrict__ W0, const float* __restrict__ W1,
    const float* __restrict__ W2, const float* __restrict__ W3,
    u16* __restrict__ D0, u16* __restrict__ D1, u16* __restrict__ D2, u16* __restrict__ D3) {
  __shared__ float tile[32][33];
  const float* W; u16* D;
  switch (blockIdx.z) {
    case 0:  W = W0; D = D0; break;
    case 1:  W = W1; D = D1; break;
    case 2:  W = W2; D = D2; break;
    default: W = W3; D = D3; break;
  }
  int n0 = blockIdx.x * 32, k0 = blockIdx.y * 32;
  int tx = threadIdx.x & 31, ty = threadIdx.x >> 5;
#pragma unroll
  for (int i = ty; i < 32; i += 8)
    tile[i][tx] = W[(long)(k0 + i) * EMB + n0 + tx];
  __syncthreads();
#pragma unroll
  for (int i = ty; i < 32; i += 8)
    D[(long)(n0 + i) * EMB + k0 + tx] = f2b(tile[tx][i]);
}

// ---------------- bf16 GEMM: C(MxN) = A(MxK) * Bt(NxK)^T + bias ----------------
#define BM 128
#define BN 128
#define BK 64
#define PB16 136   // bf16 bounce pitch (u16), 272B rows: 16B-aligned, 2-way banks on read
#define PF32 132   // f32 bounce pitch (floats), 528B rows: 16B-aligned

__global__ __launch_bounds__(256) void gemm_bt_kernel(
    const u16* __restrict__ A, const u16* __restrict__ Bt,
    const float* __restrict__ b0, const float* __restrict__ b1, const float* __restrict__ b2,
    void* __restrict__ Cp, int M, int N, int K, int out_f32) {
  // staging (2x 16KB) and epilogue bounce share this buffer
  __shared__ u16 smem[17408];   // 34816 B >= max(32768 stage, 128*136*2, 64*132*4)
  u16* lA = smem;
  u16* lB = smem + BM * BK;

  const int tid = threadIdx.x;
  const int w = tid >> 6, lane = tid & 63;
  const int nbn = N / BN;
  const int bm = blockIdx.x / nbn, bn = blockIdx.x % nbn;

  const int rw = (w >> 1) * 64;
  const int cw = (w & 1) * 64;

  f32x4 acc[4][4];
#pragma unroll
  for (int m = 0; m < 4; m++)
#pragma unroll
    for (int n = 0; n < 4; n++) acc[m][n] = (f32x4)0.0f;

  // staging: wave-uniform LDS base + lane*16B, inverse-swizzled global source
  const int srow = w * 32 + (lane >> 3);               // + i*8
  const int schunk = (lane & 7) ^ (lane >> 3);         // pre-swizzled source chunk
  const long arow_base = (long)(bm * BM + srow) * K;
  const long brow_base = (long)(bn * BN + srow) * K;

  const int frow = lane & 15;
  const int fg = lane >> 4;

  for (int k0 = 0; k0 < K; k0 += BK) {
#pragma unroll
    for (int i = 0; i < 4; i++) {
      gld_lds16(A + arow_base + (long)i * 8 * K + k0 + schunk * 8,
                &lA[(w * 32 + i * 8) * BK]);
      gld_lds16(Bt + brow_base + (long)i * 8 * K + k0 + schunk * 8,
                &lB[(w * 32 + i * 8) * BK]);
    }
    __syncthreads();
#pragma unroll
    for (int kk = 0; kk < 2; kk++) {
      s16x8 af[4], bfr[4];
#pragma unroll
      for (int m = 0; m < 4; m++) {
        int r = rw + 16 * m + frow;
        int ch = (fg + 4 * kk) ^ (r & 7);
        af[m] = *(const s16x8*)&lA[r * BK + ch * 8];
      }
#pragma unroll
      for (int n = 0; n < 4; n++) {
        int r = cw + 16 * n + frow;
        int ch = (fg + 4 * kk) ^ (r & 7);
        bfr[n] = *(const s16x8*)&lB[r * BK + ch * 8];
      }
#pragma unroll
      for (int m = 0; m < 4; m++)
#pragma unroll
        for (int n = 0; n < 4; n++)
          acc[m][n] = MFMA_BF16(af[m], bfr[n], acc[m][n]);
    }
    __syncthreads();
  }

  // ---- epilogue via LDS bounce: full-sector coalesced stores ----
  // C/D layout: col = lane&15, row = (lane>>4)*4 + reg
  const int gc0 = bn * BN + cw + frow;
  const long crow0 = (long)(bm * BM) * N + bn * BN;

  if (!out_f32) {
    u16* bb = smem;   // [128][PB16]
#pragma unroll
    for (int n = 0; n < 4; n++) {
      int gc = gc0 + 16 * n;
      int which = gc >> 10;
      const float* bias = (which == 0) ? b0 : ((which == 1) ? b1 : b2);
      float bv = bias[gc & 1023];
#pragma unroll
      for (int m = 0; m < 4; m++)
#pragma unroll
        for (int r = 0; r < 4; r++)
          bb[(rw + 16 * m + 4 * fg + r) * PB16 + cw + 16 * n + frow] = f2b(acc[m][n][r] + bv);
    }
    __syncthreads();
#pragma unroll
    for (int i = 0; i < 8; i++) {
      int flat = tid + 256 * i;
      int row = flat >> 4, ch = flat & 15;
      *(s16x8*)((u16*)Cp + crow0 + (long)row * N + ch * 8) =
          *(const s16x8*)&bb[row * PB16 + ch * 8];
    }
  } else {
    float* fb = (float*)smem;  // [64][PF32], two passes of 64 rows
#pragma unroll
    for (int p = 0; p < 2; p++) {
      if ((w >> 1) == p) {
#pragma unroll
        for (int n = 0; n < 4; n++) {
          float bv = b0[(gc0 + 16 * n) & 1023];
#pragma unroll
          for (int m = 0; m < 4; m++)
#pragma unroll
            for (int r = 0; r < 4; r++)
              fb[(16 * m + 4 * fg + r) * PF32 + cw + 16 * n + frow] = acc[m][n][r] + bv;
        }
      }
      __syncthreads();
#pragma unroll
      for (int i = 0; i < 8; i++) {
        int flat = tid + 256 * i;
        int row = flat >> 5, ch = flat & 31;
        *(float4*)((float*)Cp + crow0 + (long)(p * 64 + row) * N + ch * 4) =
            *(const float4*)&fb[row * PF32 + ch * 4];
      }
      __syncthreads();
    }
  }
}

// ---------------- local attention ----------------
#define QBLK 128
#define LPITCH 72

__global__ __launch_bounds__(256) void attn_kernel(const u16* __restrict__ QKV,
                                                   u16* __restrict__ Oa) {
  __shared__ u16 lK[64 * LPITCH];
  __shared__ u16 lV[64 * LPITCH];          // transposed: lV[d][kv ^ 8*(d>>3)]
  __shared__ u16 lP[4 * 32 * LPITCH];

  const int tid = threadIdx.x;
  const int w = tid >> 6, lane = tid & 63;
  const int frow = lane & 15, fg = lane >> 4;

  const int nq = S_LEN / QBLK;             // 32
  const int bid = blockIdx.x;
  const int b = bid / (NH * nq);
  const int rem = bid % (NH * nq);
  const int h = rem / nq;
  const int qt = rem % nq;
  const int q0 = qt * QBLK;
  const int qw0 = q0 + 32 * w;

  const u16* base = QKV + (long)b * S_LEN * 3072 + h * 64;

  s16x8 qf[2][2];
#pragma unroll
  for (int m = 0; m < 2; m++)
#pragma unroll
    for (int kk = 0; kk < 2; kk++)
      qf[m][kk] = *(const s16x8*)(base + (long)(qw0 + 16 * m + frow) * 3072 + kk * 32 + 8 * fg);

  f32x4 acc[2][4];
#pragma unroll
  for (int m = 0; m < 2; m++)
#pragma unroll
    for (int n = 0; n < 4; n++) acc[m][n] = (f32x4)0.0f;
  float mrow[2][4], lrow[2][4];
#pragma unroll
  for (int m = 0; m < 2; m++)
#pragma unroll
    for (int rg = 0; rg < 4; rg++) { mrow[m][rg] = -1e30f; lrow[m][rg] = 0.f; }

  u16* lPw = &lP[w * 32 * LPITCH];

  for (int t = 0; t < 6; t++) {
    const int kvb = q0 - 128 + t * 64;
    if (kvb + 63 < 0 || kvb >= S_LEN) continue;   // block-uniform
    {
      const int srow = tid >> 3;
      const int sc8 = tid & 7;
#pragma unroll
      for (int pass = 0; pass < 2; pass++) {
        int row = srow + pass * 32;
        int kv = kvb + row;
        s16x8 kd = (s16x8)0, vd = (s16x8)0;
        if (kv >= 0 && kv < S_LEN) {
          kd = *(const s16x8*)(base + 1024 + (long)kv * 3072 + sc8 * 8);
          vd = *(const s16x8*)(base + 2048 + (long)kv * 3072 + sc8 * 8);
        }
        *(s16x8*)&lK[row * LPITCH + sc8 * 8] = kd;
        // swizzled transpose store: elem (d=sc8*8+j, kv=row) at d*LPITCH + (row ^ 8*(d>>3))
        const int swz = row ^ (sc8 << 3);
#pragma unroll
        for (int j = 0; j < 8; j++) lV[(sc8 * 8 + j) * LPITCH + swz] = (u16)vd[j];
      }
    }
    __syncthreads();
    const bool active = (kvb + 63 >= qw0 - 128) && (kvb <= qw0 + 159);
    if (active) {
      f32x4 sfr[2][4];
#pragma unroll
      for (int m = 0; m < 2; m++)
#pragma unroll
        for (int n = 0; n < 4; n++) sfr[m][n] = (f32x4)0.0f;
#pragma unroll
      for (int kk = 0; kk < 2; kk++) {
        s16x8 kb[4];
#pragma unroll
        for (int n = 0; n < 4; n++)
          kb[n] = *(const s16x8*)&lK[(16 * n + frow) * LPITCH + (fg + 4 * kk) * 8];
#pragma unroll
        for (int m = 0; m < 2; m++)
#pragma unroll
          for (int n = 0; n < 4; n++)
            sfr[m][n] = MFMA_BF16(qf[m][kk], kb[n], sfr[m][n]);
      }
#pragma unroll
      for (int m = 0; m < 2; m++) {
#pragma unroll
        for (int rg = 0; rg < 4; rg++) {
          const int q = qw0 + 16 * m + 4 * fg + rg;
          float sv[4];
          float smax = -1e30f;
#pragma unroll
          for (int n = 0; n < 4; n++) {
            int kv = kvb + 16 * n + frow;
            bool valid = (kv >= q - 128) && (kv <= q + 128) && (kv >= 0) && (kv < S_LEN);
            float xv = valid ? sfr[m][n][rg] * 0.125f : -1e30f;
            sv[n] = xv;
            smax = fmaxf(smax, xv);
          }
          smax = fmaxf(smax, __shfl_xor(smax, 1));
          smax = fmaxf(smax, __shfl_xor(smax, 2));
          smax = fmaxf(smax, __shfl_xor(smax, 4));
          smax = fmaxf(smax, __shfl_xor(smax, 8));
          float mold = mrow[m][rg];
          float mnew = fmaxf(mold, smax);
          float alpha = __expf(mold - mnew);
          mrow[m][rg] = mnew;
          float psum = 0.f;
#pragma unroll
          for (int n = 0; n < 4; n++) {
            float p = (sv[n] > -1e29f) ? __expf(sv[n] - mnew) : 0.f;
            psum += p;
            lPw[(16 * m + 4 * fg + rg) * LPITCH + 16 * n + frow] = f2b(p);
          }
          psum += __shfl_xor(psum, 1);
          psum += __shfl_xor(psum, 2);
          psum += __shfl_xor(psum, 4);
          psum += __shfl_xor(psum, 8);
          lrow[m][rg] = lrow[m][rg] * alpha + psum;
#pragma unroll
          for (int n = 0; n < 4; n++) acc[m][n][rg] *= alpha;
        }
      }
      __threadfence_block();
#pragma unroll
      for (int kt = 0; kt < 2; kt++) {
        s16x8 pa[2], vb[4];
#pragma unroll
        for (int m = 0; m < 2; m++)
          pa[m] = *(const s16x8*)&lPw[(16 * m + frow) * LPITCH + (fg + 4 * kt) * 8];
#pragma unroll
        for (int n = 0; n < 4; n++) {
          const int d = 16 * n + frow;
          const int key = (d >> 3) & 7;
          const int o = (fg + 4 * kt) ^ key;
          vb[n] = *(const s16x8*)&lV[d * LPITCH + o * 8];
        }
#pragma unroll
        for (int m = 0; m < 2; m++)
#pragma unroll
          for (int n = 0; n < 4; n++)
            acc[m][n] = MFMA_BF16(pa[m], vb[n], acc[m][n]);
      }
    }
    __syncthreads();
  }

  // ---- epilogue: wave-private LDS bounce -> coalesced short8 stores ----
#pragma unroll
  for (int m = 0; m < 2; m++)
#pragma unroll
    for (int rg = 0; rg < 4; rg++) {
      const float inv = 1.0f / lrow[m][rg];
#pragma unroll
      for (int n = 0; n < 4; n++)
        lPw[(16 * m + 4 * fg + rg) * LPITCH + 16 * n + frow] = f2b(acc[m][n][rg] * inv);
    }
  asm volatile("s_waitcnt lgkmcnt(0)" ::: "memory");   // wave-private RAW
  u16* Ob = Oa + ((long)(b * S_LEN + qw0)) * EMB + h * HD;
#pragma unroll
  for (int i = 0; i < 4; i++) {
    int flat = lane + 64 * i;
    int row = flat >> 3, ch = flat & 7;
    *(s16x8*)(Ob + (long)row * EMB + ch * 8) = *(const s16x8*)&lPw[row * LPITCH + ch * 8];
  }
}

extern "C" void kernel_launch(void* const* d_in, const int* in_sizes, int n_in,
                              void* d_out, int out_size, void* d_ws, size_t ws_size,
                              hipStream_t stream) {
  const float* x  = (const float*)d_in[0];
  const float* Wq = (const float*)d_in[1];
  const float* bq = (const float*)d_in[2];
  const float* Wk = (const float*)d_in[3];
  const float* bk = (const float*)d_in[4];
  const float* Wv = (const float*)d_in[5];
  const float* bv = (const float*)d_in[6];
  const float* Wo = (const float*)d_in[7];
  const float* bo = (const float*)d_in[8];

  char* ws = (char*)d_ws;
  u16* xb   = (u16*)ws;  ws += (size_t)NROWS * EMB * 2;        // 32 MB
  u16* Wt   = (u16*)ws;  ws += (size_t)3 * EMB * EMB * 2;      // 6 MB
  u16* Wot  = (u16*)ws;  ws += (size_t)EMB * EMB * 2;          // 2 MB
  u16* QKVb = (u16*)ws;  ws += (size_t)NROWS * 3 * EMB * 2;    // 96 MB
  u16* Oab  = (u16*)ws;  ws += (size_t)NROWS * EMB * 2;        // 32 MB

  cvt_x_kernel<<<(NROWS * EMB) / (256 * 8), 256, 0, stream>>>(x, xb);

  dim3 tg(EMB / 32, EMB / 32, 4);
  transpose_cvt4_kernel<<<tg, 256, 0, stream>>>(
      Wq, Wk, Wv, Wo, Wt, Wt + (size_t)EMB * EMB, Wt + (size_t)2 * EMB * EMB, Wot);

  gemm_bt_kernel<<<(NROWS / BM) * (3 * EMB / BN), 256, 0, stream>>>(
      xb, Wt, bq, bk, bv, QKVb, NROWS, 3 * EMB, EMB, 0);

  attn_kernel<<<NB * NH * (S_LEN / QBLK), 256, 0, stream>>>(QKVb, Oab);

  gemm_bt_kernel<<<(NROWS / BM) * (EMB / BN), 256, 0, stream>>>(
      Oab, Wot, bo, bo, bo, d_out, NROWS, EMB, EMB, 1);
}

// Round 3
// 288.497 us; speedup vs baseline: 1.2605x; 1.1491x over previous
//
#include <hip/hip_runtime.h>
#include <hip/hip_bf16.h>
#include <type_traits>

typedef unsigned short u16;
typedef __attribute__((ext_vector_type(8))) short  s16x8;
typedef __attribute__((ext_vector_type(8))) __bf16 b16x8;
typedef __attribute__((ext_vector_type(4))) float  f32x4;

#define S_LEN 4096
#define NB    4
#define EMB   1024
#define NH    16
#define HD    64
#define NROWS (NB * S_LEN)   // 16384
#define KDIM  1024

static __device__ __forceinline__ u16 f2b(float f) {
  __hip_bfloat16 h = __float2bfloat16(f);
  return __builtin_bit_cast(u16, h);
}

// ---- MFMA shim: works whether the builtin takes short8 or bf16x8 ----
template <typename T, typename = void>
struct mfma_takes : std::false_type {};
template <typename T>
struct mfma_takes<T, std::void_t<decltype(__builtin_amdgcn_mfma_f32_16x16x32_bf16(
    std::declval<T>(), std::declval<T>(), std::declval<f32x4>(), 0, 0, 0))>> : std::true_type {};

template <typename AB>
static __device__ __forceinline__ f32x4 mfma_any(AB a, AB b, f32x4 c) {
  return __builtin_amdgcn_mfma_f32_16x16x32_bf16(a, b, c, 0, 0, 0);
}

template <typename S8 = s16x8, typename B8 = b16x8>
static __device__ __forceinline__ f32x4 MFMA_BF16(s16x8 a, s16x8 b, f32x4 c) {
  if constexpr (mfma_takes<S8>::value)
    return mfma_any<S8>(__builtin_bit_cast(S8, a), __builtin_bit_cast(S8, b), c);
  else
    return mfma_any<B8>(__builtin_bit_cast(B8, a), __builtin_bit_cast(B8, b), c);
}

static __device__ __forceinline__ void gld_lds16(const void* g, void* l) {
  __builtin_amdgcn_global_load_lds((const __attribute__((address_space(1))) void*)g,
                                   (__attribute__((address_space(3))) void*)l, 16, 0, 0);
}

// ---------------- fp32 -> bf16 conversion (x) ----------------
__global__ __launch_bounds__(256) void cvt_x_kernel(const float* __restrict__ in,
                                                    u16* __restrict__ out) {
  long i = ((long)blockIdx.x * 256 + threadIdx.x) * 8;
  float4 a = *(const float4*)(in + i);
  float4 b = *(const float4*)(in + i + 4);
  s16x8 o;
  o[0] = (short)f2b(a.x); o[1] = (short)f2b(a.y); o[2] = (short)f2b(a.z); o[3] = (short)f2b(a.w);
  o[4] = (short)f2b(b.x); o[5] = (short)f2b(b.y); o[6] = (short)f2b(b.z); o[7] = (short)f2b(b.w);
  *(s16x8*)(out + i) = o;
}

// ---------------- transpose + convert 4 x W (1024x1024), fused ----------------
__global__ __launch_bounds__(256) void transpose_cvt4_kernel(
    const float* __restrict__ W0, const float* __restrict__ W1,
    const float* __restrict__ W2, const float* __restrict__ W3,
    u16* __restrict__ D0, u16* __restrict__ D1, u16* __restrict__ D2, u16* __restrict__ D3) {
  __shared__ float tile[32][33];
  const float* W; u16* D;
  switch (blockIdx.z) {
    case 0:  W = W0; D = D0; break;
    case 1:  W = W1; D = D1; break;
    case 2:  W = W2; D = D2; break;
    default: W = W3; D = D3; break;
  }
  int n0 = blockIdx.x * 32, k0 = blockIdx.y * 32;
  int tx = threadIdx.x & 31, ty = threadIdx.x >> 5;
#pragma unroll
  for (int i = ty; i < 32; i += 8)
    tile[i][tx] = W[(long)(k0 + i) * EMB + n0 + tx];
  __syncthreads();
#pragma unroll
  for (int i = ty; i < 32; i += 8)
    D[(long)(n0 + i) * EMB + k0 + tx] = f2b(tile[tx][i]);
}

// ================= 256x256 8-phase GEMM: C = A(Mx1024) * Bt(Nx1024)^T + bias =================
// 8 waves (2M x 4N), per-wave C = 128x64. K-tile = 64, split in kk-halves of 32.
// LDS slots (16KB each, u16 units): lA[par][kk] @ (par*2+kk)*8192 ; lB[par][kk] @ 32768 + same.
// Per iteration (2 K-tiles t=2i par0, t+1 par1), phase -> {compute slot | stage target}:
//   P1 (p0,k0,mh0)|A(t+1,k1)->SA(1,1)   P2 (p0,k0,mh1)|B(t+1,k1)->SB(1,1) vm8
//   P3 (p0,k1,mh0)|A(t+2,k0)->SA(0,0)   P4 (p0,k1,mh1)|B(t+2,k0)->SB(0,0) vm8
//   P5 (p1,k0,mh0)|A(t+2,k1)->SA(0,1)   P6 (p1,k0,mh1)|B(t+2,k1)->SB(0,1) vm8
//   P7 (p1,k1,mh0)|A(t+3,k0)->SA(1,0)   P8 (p1,k1,mh1)|B(t+3,k0)->SB(1,0) vm8
// WAR: each slot's stage issues >=1 barrier after its last read. RAW: vmcnt(8) at even-phase
// end guarantees loads issued 4+ stage-phases ago have landed (2 loads/thread per stage).
#define SA_(p,k) (((p)*2+(k))*8192)
#define SB_(p,k) (32768 + ((p)*2+(k))*8192)

__global__ __launch_bounds__(512, 2) void gemm8p_kernel(
    const u16* __restrict__ A, const u16* __restrict__ Bt,
    const float* __restrict__ b0, const float* __restrict__ b1, const float* __restrict__ b2,
    void* __restrict__ Cp, int N, int out_f32) {
  __shared__ __align__(16) u16 smem[65536];   // 128 KiB
  const int tid = threadIdx.x;
  const int w = tid >> 6, lane = tid & 63;
  const int wm = w >> 2, wn = w & 3;
  const int frow = lane & 15, fg = lane >> 4;

  // XCD-aware swizzle (gridDim.x % 8 == 0 for all our launches)
  const int nwg = gridDim.x;
  const int bid = ((int)blockIdx.x & 7) * (nwg >> 3) + ((int)blockIdx.x >> 3);
  const int nbn = N >> 8;
  const int bm = bid / nbn, bn = bid % nbn;

  // fragment read offsets (u16 units within a slot); chunk XOR-swizzle (row^(row>>2))&3
  int offA[8];
#pragma unroll
  for (int j = 0; j < 8; j++) {
    int row = wm * 128 + j * 16 + frow;
    offA[j] = row * 32 + ((fg ^ ((row ^ (row >> 2)) & 3)) << 3);
  }
  int offB[4];
#pragma unroll
  for (int j = 0; j < 4; j++) {
    int row = wn * 64 + j * 16 + frow;
    offB[j] = row * 32 + ((fg ^ ((row ^ (row >> 2)) & 3)) << 3);
  }
  // staging source offsets: LDS dest is linear; source chunk pre-swizzled (involution)
  int srow[2], soff[2];
#pragma unroll
  for (int L = 0; L < 2; L++) {
    int lin = L * 512 + tid;
    int r = lin >> 2;
    srow[L] = r;
    soff[L] = (((lin & 3) ^ ((r ^ (r >> 2)) & 3)) << 3);
  }
  const u16* Abase = A + (long)bm * 256 * KDIM;
  const u16* Bbase = Bt + (long)bn * 256 * KDIM;

  f32x4 acc[8][4];
#pragma unroll
  for (int m = 0; m < 8; m++)
#pragma unroll
    for (int n = 0; n < 4; n++) acc[m][n] = (f32x4)0.0f;

  auto STAGE = [&](const u16* gb, int kcol, int slot) {
#pragma unroll
    for (int L = 0; L < 2; L++)
      gld_lds16(gb + (long)srow[L] * KDIM + kcol + soff[L],
                &smem[slot + (L * 512 + w * 64) * 8]);
  };

  s16x8 af[4], bf[4];

  // ---- prologue: stage T0.k0, T0.k1, T1.k0 (12 loads); need T0.k0 landed -> vmcnt(8)
  STAGE(Abase, 0,  SA_(0,0)); STAGE(Bbase, 0,  SB_(0,0));
  STAGE(Abase, 32, SA_(0,1)); STAGE(Bbase, 32, SB_(0,1));
  STAGE(Abase, 64, SA_(1,0)); STAGE(Bbase, 64, SB_(1,0));
  asm volatile("s_waitcnt vmcnt(8)" ::: "memory");
  asm volatile("s_barrier" ::: "memory");

#define PHASE(p, k, mh, RDB, GB, KCOL, SLOT, DOVM)                            \
  {                                                                           \
    if (RDB) {                                                                \
      _Pragma("unroll") for (int n = 0; n < 4; n++)                           \
        bf[n] = *(const s16x8*)&smem[SB_(p, k) + offB[n]];                    \
    }                                                                         \
    _Pragma("unroll") for (int m = 0; m < 4; m++)                             \
      af[m] = *(const s16x8*)&smem[SA_(p, k) + offA[(mh) * 4 + m]];           \
    STAGE(GB, KCOL, SLOT);                                                    \
    asm volatile("s_barrier" ::: "memory");                                   \
    asm volatile("s_waitcnt lgkmcnt(0)" ::: "memory");                        \
    __builtin_amdgcn_sched_barrier(0);                                        \
    __builtin_amdgcn_s_setprio(1);                                            \
    _Pragma("unroll") for (int m = 0; m < 4; m++)                             \
      _Pragma("unroll") for (int n = 0; n < 4; n++)                           \
        acc[(mh) * 4 + m][n] = MFMA_BF16(af[m], bf[n], acc[(mh) * 4 + m][n]); \
    __builtin_amdgcn_s_setprio(0);                                            \
    if (DOVM) asm volatile("s_waitcnt vmcnt(8)" ::: "memory");                \
    asm volatile("s_barrier" ::: "memory");                                   \
  }

#pragma unroll 1
  for (int i = 0; i < 8; i++) {
    const int t = 2 * i;
    const int k1 = ((t + 1) & 15) * 64;
    const int k2 = ((t + 2) & 15) * 64;   // wraps harmlessly on last iter (data unused)
    const int k3 = ((t + 3) & 15) * 64;
    PHASE(0, 0, 0, 1, Abase, k1 + 32, SA_(1, 1), 0)
    PHASE(0, 0, 1, 0, Bbase, k1 + 32, SB_(1, 1), 1)
    PHASE(0, 1, 0, 1, Abase, k2,      SA_(0, 0), 0)
    PHASE(0, 1, 1, 0, Bbase, k2,      SB_(0, 0), 1)
    PHASE(1, 0, 0, 1, Abase, k2 + 32, SA_(0, 1), 0)
    PHASE(1, 0, 1, 0, Bbase, k2 + 32, SB_(0, 1), 1)
    PHASE(1, 1, 0, 1, Abase, k3,      SA_(1, 0), 0)
    PHASE(1, 1, 1, 0, Bbase, k3,      SB_(1, 0), 1)
  }
#undef PHASE

  // drain outstanding stages before reusing LDS for the epilogue bounce
  asm volatile("s_waitcnt vmcnt(0)" ::: "memory");
  asm volatile("s_barrier" ::: "memory");

  // ---- epilogue: wave-private bounce -> coalesced stores
  // C/D frag layout: row = ...mf*16 + 4*fg + r, col = ...n*16 + frow
  const long crow0 = (long)(bm * 256) * N + bn * 256;
  if (!out_f32) {
    u16* buf = &smem[w * 4096];          // 16 x 72 u16 per wave
#pragma unroll
    for (int mf = 0; mf < 8; mf++) {
#pragma unroll
      for (int n = 0; n < 4; n++) {
        int gc = bn * 256 + wn * 64 + n * 16 + frow;
        int which = gc >> 10;
        const float* bias = (which == 0) ? b0 : ((which == 1) ? b1 : b2);
        float bv = bias[gc & 1023];
#pragma unroll
        for (int r = 0; r < 4; r++)
          buf[(4 * fg + r) * 72 + n * 16 + frow] = f2b(acc[mf][n][r] + bv);
      }
      asm volatile("s_waitcnt lgkmcnt(0)" ::: "memory");
      __builtin_amdgcn_sched_barrier(0);
#pragma unroll
      for (int q = 0; q < 2; q++) {
        int row = q * 8 + (lane >> 3);
        int ch = lane & 7;
        s16x8 v = *(const s16x8*)&buf[row * 72 + ch * 8];
        long gr = (long)(wm * 128 + mf * 16 + row);
        *(s16x8*)((u16*)Cp + crow0 + gr * N + wn * 64 + ch * 8) = v;
      }
      asm volatile("s_waitcnt lgkmcnt(0)" ::: "memory");
      __builtin_amdgcn_sched_barrier(0);
    }
  } else {
    float* fbuf = (float*)&smem[w * 4096];   // 16 x 68 f32 per wave (fits 8KB)
#pragma unroll
    for (int mf = 0; mf < 8; mf++) {
#pragma unroll
      for (int n = 0; n < 4; n++) {
        float bv = b0[(bn * 256 + wn * 64 + n * 16 + frow) & 1023];
#pragma unroll
        for (int r = 0; r < 4; r++)
          fbuf[(4 * fg + r) * 68 + n * 16 + frow] = acc[mf][n][r] + bv;
      }
      asm volatile("s_waitcnt lgkmcnt(0)" ::: "memory");
      __builtin_amdgcn_sched_barrier(0);
#pragma unroll
      for (int q = 0; q < 4; q++) {
        int row = q * 4 + (lane >> 4);
        int ch = lane & 15;
        float4 v = *(const float4*)&fbuf[row * 68 + ch * 4];
        long gr = (long)(wm * 128 + mf * 16 + row);
        *(float4*)((float*)Cp + crow0 + gr * N + wn * 64 + ch * 4) = v;
      }
      asm volatile("s_waitcnt lgkmcnt(0)" ::: "memory");
      __builtin_amdgcn_sched_barrier(0);
    }
  }
}

// ---------------- local attention ----------------
#define QBLK 128
#define LPITCH 72

__global__ __launch_bounds__(256) void attn_kernel(const u16* __restrict__ QKV,
                                                   u16* __restrict__ Oa) {
  __shared__ u16 lK[64 * LPITCH];
  __shared__ u16 lV[64 * LPITCH];          // transposed: lV[d][kv ^ 8*(d>>3)]
  __shared__ u16 lP[4 * 32 * LPITCH];

  const int tid = threadIdx.x;
  const int w = tid >> 6, lane = tid & 63;
  const int frow = lane & 15, fg = lane >> 4;

  const int nq = S_LEN / QBLK;             // 32
  const int bid = blockIdx.x;
  const int b = bid / (NH * nq);
  const int rem = bid % (NH * nq);
  const int h = rem / nq;
  const int qt = rem % nq;
  const int q0 = qt * QBLK;
  const int qw0 = q0 + 32 * w;

  const u16* base = QKV + (long)b * S_LEN * 3072 + h * 64;

  s16x8 qf[2][2];
#pragma unroll
  for (int m = 0; m < 2; m++)
#pragma unroll
    for (int kk = 0; kk < 2; kk++)
      qf[m][kk] = *(const s16x8*)(base + (long)(qw0 + 16 * m + frow) * 3072 + kk * 32 + 8 * fg);

  f32x4 acc[2][4];
#pragma unroll
  for (int m = 0; m < 2; m++)
#pragma unroll
    for (int n = 0; n < 4; n++) acc[m][n] = (f32x4)0.0f;
  float mrow[2][4], lrow[2][4];
#pragma unroll
  for (int m = 0; m < 2; m++)
#pragma unroll
    for (int rg = 0; rg < 4; rg++) { mrow[m][rg] = -1e30f; lrow[m][rg] = 0.f; }

  u16* lPw = &lP[w * 32 * LPITCH];

  for (int t = 0; t < 6; t++) {
    const int kvb = q0 - 128 + t * 64;
    if (kvb + 63 < 0 || kvb >= S_LEN) continue;   // block-uniform
    {
      const int srow = tid >> 3;
      const int sc8 = tid & 7;
#pragma unroll
      for (int pass = 0; pass < 2; pass++) {
        int row = srow + pass * 32;
        int kv = kvb + row;
        s16x8 kd = (s16x8)0, vd = (s16x8)0;
        if (kv >= 0 && kv < S_LEN) {
          kd = *(const s16x8*)(base + 1024 + (long)kv * 3072 + sc8 * 8);
          vd = *(const s16x8*)(base + 2048 + (long)kv * 3072 + sc8 * 8);
        }
        *(s16x8*)&lK[row * LPITCH + sc8 * 8] = kd;
        const int swz = row ^ (sc8 << 3);
#pragma unroll
        for (int j = 0; j < 8; j++) lV[(sc8 * 8 + j) * LPITCH + swz] = (u16)vd[j];
      }
    }
    __syncthreads();
    const bool active = (kvb + 63 >= qw0 - 128) && (kvb <= qw0 + 159);
    if (active) {
      f32x4 sfr[2][4];
#pragma unroll
      for (int m = 0; m < 2; m++)
#pragma unroll
        for (int n = 0; n < 4; n++) sfr[m][n] = (f32x4)0.0f;
#pragma unroll
      for (int kk = 0; kk < 2; kk++) {
        s16x8 kb[4];
#pragma unroll
        for (int n = 0; n < 4; n++)
          kb[n] = *(const s16x8*)&lK[(16 * n + frow) * LPITCH + (fg + 4 * kk) * 8];
#pragma unroll
        for (int m = 0; m < 2; m++)
#pragma unroll
          for (int n = 0; n < 4; n++)
            sfr[m][n] = MFMA_BF16(qf[m][kk], kb[n], sfr[m][n]);
      }
#pragma unroll
      for (int m = 0; m < 2; m++) {
#pragma unroll
        for (int rg = 0; rg < 4; rg++) {
          const int q = qw0 + 16 * m + 4 * fg + rg;
          float sv[4];
          float smax = -1e30f;
#pragma unroll
          for (int n = 0; n < 4; n++) {
            int kv = kvb + 16 * n + frow;
            bool valid = (kv >= q - 128) && (kv <= q + 128) && (kv >= 0) && (kv < S_LEN);
            float xv = valid ? sfr[m][n][rg] * 0.125f : -1e30f;
            sv[n] = xv;
            smax = fmaxf(smax, xv);
          }
          smax = fmaxf(smax, __shfl_xor(smax, 1));
          smax = fmaxf(smax, __shfl_xor(smax, 2));
          smax = fmaxf(smax, __shfl_xor(smax, 4));
          smax = fmaxf(smax, __shfl_xor(smax, 8));
          float mold = mrow[m][rg];
          float mnew = fmaxf(mold, smax);
          float alpha = __expf(mold - mnew);
          mrow[m][rg] = mnew;
          float psum = 0.f;
#pragma unroll
          for (int n = 0; n < 4; n++) {
            float p = (sv[n] > -1e29f) ? __expf(sv[n] - mnew) : 0.f;
            psum += p;
            lPw[(16 * m + 4 * fg + rg) * LPITCH + 16 * n + frow] = f2b(p);
          }
          psum += __shfl_xor(psum, 1);
          psum += __shfl_xor(psum, 2);
          psum += __shfl_xor(psum, 4);
          psum += __shfl_xor(psum, 8);
          lrow[m][rg] = lrow[m][rg] * alpha + psum;
#pragma unroll
          for (int n = 0; n < 4; n++) acc[m][n][rg] *= alpha;
        }
      }
      __threadfence_block();
#pragma unroll
      for (int kt = 0; kt < 2; kt++) {
        s16x8 pa[2], vb[4];
#pragma unroll
        for (int m = 0; m < 2; m++)
          pa[m] = *(const s16x8*)&lPw[(16 * m + frow) * LPITCH + (fg + 4 * kt) * 8];
#pragma unroll
        for (int n = 0; n < 4; n++) {
          const int d = 16 * n + frow;
          const int key = (d >> 3) & 7;
          const int o = (fg + 4 * kt) ^ key;
          vb[n] = *(const s16x8*)&lV[d * LPITCH + o * 8];
        }
#pragma unroll
        for (int m = 0; m < 2; m++)
#pragma unroll
          for (int n = 0; n < 4; n++)
            acc[m][n] = MFMA_BF16(pa[m], vb[n], acc[m][n]);
      }
    }
    __syncthreads();
  }

  // ---- epilogue: wave-private LDS bounce -> coalesced short8 stores ----
#pragma unroll
  for (int m = 0; m < 2; m++)
#pragma unroll
    for (int rg = 0; rg < 4; rg++) {
      const float inv = 1.0f / lrow[m][rg];
#pragma unroll
      for (int n = 0; n < 4; n++)
        lPw[(16 * m + 4 * fg + rg) * LPITCH + 16 * n + frow] = f2b(acc[m][n][rg] * inv);
    }
  asm volatile("s_waitcnt lgkmcnt(0)" ::: "memory");   // wave-private RAW
  u16* Ob = Oa + ((long)(b * S_LEN + qw0)) * EMB + h * HD;
#pragma unroll
  for (int i = 0; i < 4; i++) {
    int flat = lane + 64 * i;
    int row = flat >> 3, ch = flat & 7;
    *(s16x8*)(Ob + (long)row * EMB + ch * 8) = *(const s16x8*)&lPw[row * LPITCH + ch * 8];
  }
}

extern "C" void kernel_launch(void* const* d_in, const int* in_sizes, int n_in,
                              void* d_out, int out_size, void* d_ws, size_t ws_size,
                              hipStream_t stream) {
  const float* x  = (const float*)d_in[0];
  const float* Wq = (const float*)d_in[1];
  const float* bq = (const float*)d_in[2];
  const float* Wk = (const float*)d_in[3];
  const float* bk = (const float*)d_in[4];
  const float* Wv = (const float*)d_in[5];
  const float* bv = (const float*)d_in[6];
  const float* Wo = (const float*)d_in[7];
  const float* bo = (const float*)d_in[8];

  char* ws = (char*)d_ws;
  u16* xb   = (u16*)ws;  ws += (size_t)NROWS * EMB * 2;        // 32 MB
  u16* Wt   = (u16*)ws;  ws += (size_t)3 * EMB * EMB * 2;      // 6 MB
  u16* Wot  = (u16*)ws;  ws += (size_t)EMB * EMB * 2;          // 2 MB
  u16* QKVb = (u16*)ws;  ws += (size_t)NROWS * 3 * EMB * 2;    // 96 MB
  u16* Oab  = (u16*)ws;  ws += (size_t)NROWS * EMB * 2;        // 32 MB

  cvt_x_kernel<<<(NROWS * EMB) / (256 * 8), 256, 0, stream>>>(x, xb);

  dim3 tg(EMB / 32, EMB / 32, 4);
  transpose_cvt4_kernel<<<tg, 256, 0, stream>>>(
      Wq, Wk, Wv, Wo, Wt, Wt + (size_t)EMB * EMB, Wt + (size_t)2 * EMB * EMB, Wot);

  // QKV projection: M=16384, N=3072 -> 64 x 12 = 768 blocks (%8==0)
  gemm8p_kernel<<<(NROWS / 256) * (3 * EMB / 256), 512, 0, stream>>>(
      xb, Wt, bq, bk, bv, QKVb, 3 * EMB, 0);

  attn_kernel<<<NB * NH * (S_LEN / QBLK), 256, 0, stream>>>(QKVb, Oab);

  // Output projection: M=16384, N=1024 -> 64 x 4 = 256 blocks (%8==0)
  gemm8p_kernel<<<(NROWS / 256) * (EMB / 256), 512, 0, stream>>>(
      Oab, Wot, bo, bo, bo, d_out, EMB, 1);
}

// Round 4
// 260.076 us; speedup vs baseline: 1.3982x; 1.1093x over previous
//
#include <hip/hip_runtime.h>
#include <hip/hip_bf16.h>
#include <type_traits>

typedef unsigned short u16;
typedef __attribute__((ext_vector_type(8))) short  s16x8;
typedef __attribute__((ext_vector_type(4))) short  s16x4;
typedef __attribute__((ext_vector_type(8))) __bf16 b16x8;
typedef __attribute__((ext_vector_type(4))) float  f32x4;

#define S_LEN 4096
#define NB    4
#define EMB   1024
#define NH    16
#define HD    64
#define NROWS (NB * S_LEN)   // 16384
#define KDIM  1024

static __device__ __forceinline__ u16 f2b(float f) {
  __hip_bfloat16 h = __float2bfloat16(f);
  return __builtin_bit_cast(u16, h);
}

// ---- MFMA shim: works whether the builtin takes short8 or bf16x8 ----
template <typename T, typename = void>
struct mfma_takes : std::false_type {};
template <typename T>
struct mfma_takes<T, std::void_t<decltype(__builtin_amdgcn_mfma_f32_16x16x32_bf16(
    std::declval<T>(), std::declval<T>(), std::declval<f32x4>(), 0, 0, 0))>> : std::true_type {};

template <typename AB>
static __device__ __forceinline__ f32x4 mfma_any(AB a, AB b, f32x4 c) {
  return __builtin_amdgcn_mfma_f32_16x16x32_bf16(a, b, c, 0, 0, 0);
}

template <typename S8 = s16x8, typename B8 = b16x8>
static __device__ __forceinline__ f32x4 MFMA_BF16(s16x8 a, s16x8 b, f32x4 c) {
  if constexpr (mfma_takes<S8>::value)
    return mfma_any<S8>(__builtin_bit_cast(S8, a), __builtin_bit_cast(S8, b), c);
  else
    return mfma_any<B8>(__builtin_bit_cast(B8, a), __builtin_bit_cast(B8, b), c);
}

static __device__ __forceinline__ void gld_lds16(const void* g, void* l) {
  __builtin_amdgcn_global_load_lds((const __attribute__((address_space(1))) void*)g,
                                   (__attribute__((address_space(3))) void*)l, 16, 0, 0);
}

// ---------------- fp32 -> bf16 conversion (x) ----------------
__global__ __launch_bounds__(256) void cvt_x_kernel(const float* __restrict__ in,
                                                    u16* __restrict__ out) {
  long i = ((long)blockIdx.x * 256 + threadIdx.x) * 8;
  float4 a = *(const float4*)(in + i);
  float4 b = *(const float4*)(in + i + 4);
  s16x8 o;
  o[0] = (short)f2b(a.x); o[1] = (short)f2b(a.y); o[2] = (short)f2b(a.z); o[3] = (short)f2b(a.w);
  o[4] = (short)f2b(b.x); o[5] = (short)f2b(b.y); o[6] = (short)f2b(b.z); o[7] = (short)f2b(b.w);
  *(s16x8*)(out + i) = o;
}

// ---------------- transpose + convert 4 x W (1024x1024), fused ----------------
__global__ __launch_bounds__(256) void transpose_cvt4_kernel(
    const float* __restrict__ W0, const float* __restrict__ W1,
    const float* __restrict__ W2, const float* __restrict__ W3,
    u16* __restrict__ D0, u16* __restrict__ D1, u16* __restrict__ D2, u16* __restrict__ D3) {
  __shared__ float tile[32][33];
  const float* W; u16* D;
  switch (blockIdx.z) {
    case 0:  W = W0; D = D0; break;
    case 1:  W = W1; D = D1; break;
    case 2:  W = W2; D = D2; break;
    default: W = W3; D = D3; break;
  }
  int n0 = blockIdx.x * 32, k0 = blockIdx.y * 32;
  int tx = threadIdx.x & 31, ty = threadIdx.x >> 5;
#pragma unroll
  for (int i = ty; i < 32; i += 8)
    tile[i][tx] = W[(long)(k0 + i) * EMB + n0 + tx];
  __syncthreads();
#pragma unroll
  for (int i = ty; i < 32; i += 8)
    D[(long)(n0 + i) * EMB + k0 + tx] = f2b(tile[tx][i]);
}

// ================= 256x256 8-phase GEMM: C = A(Mx1024) * Bt(Nx1024)^T + bias =================
// (unchanged from round 3 — see phase map comment)
#define SA_(p,k) (((p)*2+(k))*8192)
#define SB_(p,k) (32768 + ((p)*2+(k))*8192)

__global__ __launch_bounds__(512, 2) void gemm8p_kernel(
    const u16* __restrict__ A, const u16* __restrict__ Bt,
    const float* __restrict__ b0, const float* __restrict__ b1, const float* __restrict__ b2,
    void* __restrict__ Cp, int N, int out_f32) {
  __shared__ __align__(16) u16 smem[65536];   // 128 KiB
  const int tid = threadIdx.x;
  const int w = tid >> 6, lane = tid & 63;
  const int wm = w >> 2, wn = w & 3;
  const int frow = lane & 15, fg = lane >> 4;

  const int nwg = gridDim.x;
  const int bid = ((int)blockIdx.x & 7) * (nwg >> 3) + ((int)blockIdx.x >> 3);
  const int nbn = N >> 8;
  const int bm = bid / nbn, bn = bid % nbn;

  int offA[8];
#pragma unroll
  for (int j = 0; j < 8; j++) {
    int row = wm * 128 + j * 16 + frow;
    offA[j] = row * 32 + ((fg ^ ((row ^ (row >> 2)) & 3)) << 3);
  }
  int offB[4];
#pragma unroll
  for (int j = 0; j < 4; j++) {
    int row = wn * 64 + j * 16 + frow;
    offB[j] = row * 32 + ((fg ^ ((row ^ (row >> 2)) & 3)) << 3);
  }
  int srow[2], soff[2];
#pragma unroll
  for (int L = 0; L < 2; L++) {
    int lin = L * 512 + tid;
    int r = lin >> 2;
    srow[L] = r;
    soff[L] = (((lin & 3) ^ ((r ^ (r >> 2)) & 3)) << 3);
  }
  const u16* Abase = A + (long)bm * 256 * KDIM;
  const u16* Bbase = Bt + (long)bn * 256 * KDIM;

  f32x4 acc[8][4];
#pragma unroll
  for (int m = 0; m < 8; m++)
#pragma unroll
    for (int n = 0; n < 4; n++) acc[m][n] = (f32x4)0.0f;

  auto STAGE = [&](const u16* gb, int kcol, int slot) {
#pragma unroll
    for (int L = 0; L < 2; L++)
      gld_lds16(gb + (long)srow[L] * KDIM + kcol + soff[L],
                &smem[slot + (L * 512 + w * 64) * 8]);
  };

  s16x8 af[4], bf[4];

  STAGE(Abase, 0,  SA_(0,0)); STAGE(Bbase, 0,  SB_(0,0));
  STAGE(Abase, 32, SA_(0,1)); STAGE(Bbase, 32, SB_(0,1));
  STAGE(Abase, 64, SA_(1,0)); STAGE(Bbase, 64, SB_(1,0));
  asm volatile("s_waitcnt vmcnt(8)" ::: "memory");
  asm volatile("s_barrier" ::: "memory");

#define PHASE(p, k, mh, RDB, GB, KCOL, SLOT, DOVM)                            \
  {                                                                           \
    if (RDB) {                                                                \
      _Pragma("unroll") for (int n = 0; n < 4; n++)                           \
        bf[n] = *(const s16x8*)&smem[SB_(p, k) + offB[n]];                    \
    }                                                                         \
    _Pragma("unroll") for (int m = 0; m < 4; m++)                             \
      af[m] = *(const s16x8*)&smem[SA_(p, k) + offA[(mh) * 4 + m]];           \
    STAGE(GB, KCOL, SLOT);                                                    \
    asm volatile("s_barrier" ::: "memory");                                   \
    asm volatile("s_waitcnt lgkmcnt(0)" ::: "memory");                        \
    __builtin_amdgcn_sched_barrier(0);                                        \
    __builtin_amdgcn_s_setprio(1);                                            \
    _Pragma("unroll") for (int m = 0; m < 4; m++)                             \
      _Pragma("unroll") for (int n = 0; n < 4; n++)                           \
        acc[(mh) * 4 + m][n] = MFMA_BF16(af[m], bf[n], acc[(mh) * 4 + m][n]); \
    __builtin_amdgcn_s_setprio(0);                                            \
    if (DOVM) asm volatile("s_waitcnt vmcnt(8)" ::: "memory");                \
    asm volatile("s_barrier" ::: "memory");                                   \
  }

#pragma unroll 1
  for (int i = 0; i < 8; i++) {
    const int t = 2 * i;
    const int k1 = ((t + 1) & 15) * 64;
    const int k2 = ((t + 2) & 15) * 64;
    const int k3 = ((t + 3) & 15) * 64;
    PHASE(0, 0, 0, 1, Abase, k1 + 32, SA_(1, 1), 0)
    PHASE(0, 0, 1, 0, Bbase, k1 + 32, SB_(1, 1), 1)
    PHASE(0, 1, 0, 1, Abase, k2,      SA_(0, 0), 0)
    PHASE(0, 1, 1, 0, Bbase, k2,      SB_(0, 0), 1)
    PHASE(1, 0, 0, 1, Abase, k2 + 32, SA_(0, 1), 0)
    PHASE(1, 0, 1, 0, Bbase, k2 + 32, SB_(0, 1), 1)
    PHASE(1, 1, 0, 1, Abase, k3,      SA_(1, 0), 0)
    PHASE(1, 1, 1, 0, Bbase, k3,      SB_(1, 0), 1)
  }
#undef PHASE

  asm volatile("s_waitcnt vmcnt(0)" ::: "memory");
  asm volatile("s_barrier" ::: "memory");

  const long crow0 = (long)(bm * 256) * N + bn * 256;
  if (!out_f32) {
    u16* buf = &smem[w * 4096];
#pragma unroll
    for (int mf = 0; mf < 8; mf++) {
#pragma unroll
      for (int n = 0; n < 4; n++) {
        int gc = bn * 256 + wn * 64 + n * 16 + frow;
        int which = gc >> 10;
        const float* bias = (which == 0) ? b0 : ((which == 1) ? b1 : b2);
        float bv = bias[gc & 1023];
#pragma unroll
        for (int r = 0; r < 4; r++)
          buf[(4 * fg + r) * 72 + n * 16 + frow] = f2b(acc[mf][n][r] + bv);
      }
      asm volatile("s_waitcnt lgkmcnt(0)" ::: "memory");
      __builtin_amdgcn_sched_barrier(0);
#pragma unroll
      for (int q = 0; q < 2; q++) {
        int row = q * 8 + (lane >> 3);
        int ch = lane & 7;
        s16x8 v = *(const s16x8*)&buf[row * 72 + ch * 8];
        long gr = (long)(wm * 128 + mf * 16 + row);
        *(s16x8*)((u16*)Cp + crow0 + gr * N + wn * 64 + ch * 8) = v;
      }
      asm volatile("s_waitcnt lgkmcnt(0)" ::: "memory");
      __builtin_amdgcn_sched_barrier(0);
    }
  } else {
    float* fbuf = (float*)&smem[w * 4096];
#pragma unroll
    for (int mf = 0; mf < 8; mf++) {
#pragma unroll
      for (int n = 0; n < 4; n++) {
        float bv = b0[(bn * 256 + wn * 64 + n * 16 + frow) & 1023];
#pragma unroll
        for (int r = 0; r < 4; r++)
          fbuf[(4 * fg + r) * 68 + n * 16 + frow] = acc[mf][n][r] + bv;
      }
      asm volatile("s_waitcnt lgkmcnt(0)" ::: "memory");
      __builtin_amdgcn_sched_barrier(0);
#pragma unroll
      for (int q = 0; q < 4; q++) {
        int row = q * 4 + (lane >> 4);
        int ch = lane & 15;
        float4 v = *(const float4*)&fbuf[row * 68 + ch * 4];
        long gr = (long)(wm * 128 + mf * 16 + row);
        *(float4*)((float*)Cp + crow0 + gr * N + wn * 64 + ch * 4) = v;
      }
      asm volatile("s_waitcnt lgkmcnt(0)" ::: "memory");
      __builtin_amdgcn_sched_barrier(0);
    }
  }
}

// ---------------- local attention (swapped QK^T, in-register P) ----------------
// S^T = mfma(K_frag, Q_frag): lane holds S[q=qw0+16m+frow][kv=kvb+16n+4*fg+r].
// PV uses k-permutation pi: k=fg*8+j <-> kv = 16*(2*kt+(j>>2)) + 4*fg + (j&3),
// applied identically to P (A-frag, in-lane) and V (B-frag, via LDS read addr).
// PV output D: row q=16m+4*fg+r, col d=16nd+frow -> alpha/inv transported by 4 shfl.
#define QBLK 128
#define LPITCH 72

__global__ __launch_bounds__(256) void attn_kernel(const u16* __restrict__ QKV,
                                                   u16* __restrict__ Oa) {
  __shared__ __align__(16) u16 smem[9216];   // lK[64][72] + lV[64][72] = 18.4 KB
  u16* lK = smem;
  u16* lV = smem + 64 * LPITCH;

  const int tid = threadIdx.x;
  const int w = tid >> 6, lane = tid & 63;
  const int frow = lane & 15, fg = lane >> 4;

  const int nq = S_LEN / QBLK;             // 32
  int bid = (int)blockIdx.x;
  bid = (bid & 7) * ((NB * NH * nq) >> 3) + (bid >> 3);   // XCD swizzle (grid%8==0)
  const int b = bid / (NH * nq);
  const int rem = bid % (NH * nq);
  const int h = rem / nq;
  const int qt = rem % nq;
  const int q0 = qt * QBLK;
  const int qw0 = q0 + 32 * w;

  const u16* base = QKV + (long)b * S_LEN * 3072 + h * 64;

  // Q fragments (A-frag layout, used as MFMA B operand)
  s16x8 qf[2][2];
#pragma unroll
  for (int m = 0; m < 2; m++)
#pragma unroll
    for (int kk = 0; kk < 2; kk++)
      qf[m][kk] = *(const s16x8*)(base + (long)(qw0 + 16 * m + frow) * 3072 + kk * 32 + 8 * fg);

  f32x4 acc[2][4];
#pragma unroll
  for (int m = 0; m < 2; m++)
#pragma unroll
    for (int n = 0; n < 4; n++) acc[m][n] = (f32x4)0.0f;
  float mrow[2] = {-1e30f, -1e30f};
  float lrow[2] = {0.f, 0.f};

  for (int t = 0; t < 6; t++) {
    const int kvb = q0 - 128 + t * 64;
    if (kvb + 63 < 0 || kvb >= S_LEN) continue;   // block-uniform
    {
      const int srowt = tid >> 3;
      const int sc8 = tid & 7;
#pragma unroll
      for (int pass = 0; pass < 2; pass++) {
        int row = srowt + pass * 32;
        int kv = kvb + row;
        s16x8 kd = (s16x8)0, vd = (s16x8)0;
        if (kv >= 0 && kv < S_LEN) {
          kd = *(const s16x8*)(base + 1024 + (long)kv * 3072 + sc8 * 8);
          vd = *(const s16x8*)(base + 2048 + (long)kv * 3072 + sc8 * 8);
        }
        *(s16x8*)&lK[row * LPITCH + sc8 * 8] = kd;
        const int swz = row ^ (sc8 << 3);   // key = ((d>>3)&7)<<3, d = sc8*8+j
#pragma unroll
        for (int j = 0; j < 8; j++) lV[(sc8 * 8 + j) * LPITCH + swz] = (u16)vd[j];
      }
    }
    __syncthreads();
    const bool active = (kvb + 63 >= qw0 - 128) && (kvb <= qw0 + 159);
    if (active) {
      // ---- QK^T (swapped): sfr[m][n] holds S[q=frow][kv=16n+4fg+r]
      f32x4 sfr[2][4];
#pragma unroll
      for (int m = 0; m < 2; m++)
#pragma unroll
        for (int n = 0; n < 4; n++) sfr[m][n] = (f32x4)0.0f;
#pragma unroll
      for (int kk = 0; kk < 2; kk++) {
        s16x8 kb[4];
#pragma unroll
        for (int n = 0; n < 4; n++)
          kb[n] = *(const s16x8*)&lK[(16 * n + frow) * LPITCH + (fg + 4 * kk) * 8];
#pragma unroll
        for (int m = 0; m < 2; m++)
#pragma unroll
          for (int n = 0; n < 4; n++)
            sfr[m][n] = MFMA_BF16(kb[n], qf[m][kk], sfr[m][n]);
      }
      // ---- per-m softmax + PV
#pragma unroll
      for (int m = 0; m < 2; m++) {
        const int q = qw0 + 16 * m + frow;
        float p[4][4];
        float tmax = -1e30f;
#pragma unroll
        for (int n = 0; n < 4; n++)
#pragma unroll
          for (int r = 0; r < 4; r++) {
            int kv = kvb + 16 * n + 4 * fg + r;
            bool valid = (kv >= q - 128) && (kv <= q + 128) && (kv >= 0) && (kv < S_LEN);
            float xv = valid ? sfr[m][n][r] * 0.125f : -1e30f;
            p[n][r] = xv;
            tmax = fmaxf(tmax, xv);
          }
        tmax = fmaxf(tmax, __shfl_xor(tmax, 16));
        tmax = fmaxf(tmax, __shfl_xor(tmax, 32));
        float mold = mrow[m];
        float mnew = fmaxf(mold, tmax);
        float al = __expf(mold - mnew);
        mrow[m] = mnew;
        float ps = 0.f;
#pragma unroll
        for (int n = 0; n < 4; n++)
#pragma unroll
          for (int r = 0; r < 4; r++) {
            float e = (p[n][r] > -1e29f) ? __expf(p[n][r] - mnew) : 0.f;
            p[n][r] = e;
            ps += e;
          }
        ps += __shfl_xor(ps, 16);
        ps += __shfl_xor(ps, 32);
        lrow[m] = lrow[m] * al + ps;
        // transport alpha to acc rows (q_local = 4*fg + r)
        float a4[4];
#pragma unroll
        for (int r = 0; r < 4; r++) a4[r] = __shfl(al, 20 * fg + r);
#pragma unroll
        for (int nd = 0; nd < 4; nd++)
#pragma unroll
          for (int r = 0; r < 4; r++) acc[m][nd][r] *= a4[r];
        // pack P A-fragments (in-lane, permutation pi)
#pragma unroll
        for (int kt = 0; kt < 2; kt++) {
          s16x8 pa;
#pragma unroll
          for (int j = 0; j < 8; j++)
            pa[j] = (short)f2b(p[2 * kt + (j >> 2)][j & 3]);
#pragma unroll
          for (int nd = 0; nd < 4; nd++) {
            const int d = 16 * nd + frow;
            const int key = ((d >> 3) & 7) << 3;
            const u16* vrow = &lV[d * LPITCH];
            const int a0 = (32 * kt + 4 * fg) ^ key;
            const int a1 = (32 * kt + 16 + 4 * fg) ^ key;
            s16x4 lo = *(const s16x4*)&vrow[a0];
            s16x4 hi = *(const s16x4*)&vrow[a1];
            s16x8 vb;
            vb[0] = lo[0]; vb[1] = lo[1]; vb[2] = lo[2]; vb[3] = lo[3];
            vb[4] = hi[0]; vb[5] = hi[1]; vb[6] = hi[2]; vb[7] = hi[3];
            acc[m][nd] = MFMA_BF16(pa, vb, acc[m][nd]);
          }
        }
      }
    }
    __syncthreads();
  }

  // ---- epilogue: normalize (inv transported like alpha), wave-private LDS bounce
  float i4[2][4];
#pragma unroll
  for (int m = 0; m < 2; m++) {
    float inv = 1.0f / lrow[m];
#pragma unroll
    for (int r = 0; r < 4; r++) i4[m][r] = __shfl(inv, 20 * fg + r);
  }
  u16* bb = smem + w * 2304;   // 32 rows x 72
#pragma unroll
  for (int m = 0; m < 2; m++)
#pragma unroll
    for (int nd = 0; nd < 4; nd++)
#pragma unroll
      for (int r = 0; r < 4; r++)
        bb[(16 * m + 4 * fg + r) * LPITCH + 16 * nd + frow] = f2b(acc[m][nd][r] * i4[m][r]);
  asm volatile("s_waitcnt lgkmcnt(0)" ::: "memory");
  __builtin_amdgcn_sched_barrier(0);
  u16* Ob = Oa + ((long)(b * S_LEN + qw0)) * EMB + h * HD;
#pragma unroll
  for (int i = 0; i < 4; i++) {
    int flat = lane + 64 * i;
    int row = flat >> 3, ch = flat & 7;
    *(s16x8*)(Ob + (long)row * EMB + ch * 8) = *(const s16x8*)&bb[row * LPITCH + ch * 8];
  }
}

extern "C" void kernel_launch(void* const* d_in, const int* in_sizes, int n_in,
                              void* d_out, int out_size, void* d_ws, size_t ws_size,
                              hipStream_t stream) {
  const float* x  = (const float*)d_in[0];
  const float* Wq = (const float*)d_in[1];
  const float* bq = (const float*)d_in[2];
  const float* Wk = (const float*)d_in[3];
  const float* bk = (const float*)d_in[4];
  const float* Wv = (const float*)d_in[5];
  const float* bv = (const float*)d_in[6];
  const float* Wo = (const float*)d_in[7];
  const float* bo = (const float*)d_in[8];

  char* ws = (char*)d_ws;
  u16* xb   = (u16*)ws;  ws += (size_t)NROWS * EMB * 2;        // 32 MB
  u16* Wt   = (u16*)ws;  ws += (size_t)3 * EMB * EMB * 2;      // 6 MB
  u16* Wot  = (u16*)ws;  ws += (size_t)EMB * EMB * 2;          // 2 MB
  u16* QKVb = (u16*)ws;  ws += (size_t)NROWS * 3 * EMB * 2;    // 96 MB
  u16* Oab  = (u16*)ws;  ws += (size_t)NROWS * EMB * 2;        // 32 MB

  cvt_x_kernel<<<(NROWS * EMB) / (256 * 8), 256, 0, stream>>>(x, xb);

  dim3 tg(EMB / 32, EMB / 32, 4);
  transpose_cvt4_kernel<<<tg, 256, 0, stream>>>(
      Wq, Wk, Wv, Wo, Wt, Wt + (size_t)EMB * EMB, Wt + (size_t)2 * EMB * EMB, Wot);

  gemm8p_kernel<<<(NROWS / 256) * (3 * EMB / 256), 512, 0, stream>>>(
      xb, Wt, bq, bk, bv, QKVb, 3 * EMB, 0);

  attn_kernel<<<NB * NH * (S_LEN / QBLK), 256, 0, stream>>>(QKVb, Oab);

  gemm8p_kernel<<<(NROWS / 256) * (EMB / 256), 512, 0, stream>>>(
      Oab, Wot, bo, bo, bo, d_out, EMB, 1);
}